// Round 3
// baseline (22.606 us; speedup 1.0000x reference)
//
#include <hip/hip_runtime.h>

// Son_swapnet: out[b,i] = sum_j d*leaky01(t3)*(-w3[e(i,j)]),
//   d  = x[b,i]*w1[i] - x[b,j]*w1[j]
//   t3 = c0 + a*(c1 + a*(c2 + a*c3)), a = |d|
//   leaky01(t) = max(t, 0.01t)   [== leaky factor of poly = a*t3, since a>=0]
// j==i contributes exactly 0 (d==0), so the j-loop runs uniformly over all 256.

#define C_NODES 256
#define BT      64      // batches per block (one per lane)
#define NW      4       // waves per block (256 threads)
#define RPW     2       // nodes per wave
#define NPB     (NW*RPW) // 8 nodes per block

__global__ __launch_bounds__(256, 2) void son_kernel(
    const float* __restrict__ x, const float* __restrict__ w1,
    const float* __restrict__ w2, const float* __restrict__ w3,
    float* __restrict__ out)
{
    // o1t: [row=batch][channel], 256 words/row, 16B-chunk XOR-swizzled by (row&7)
    __shared__ __align__(16) float o1t[BT * C_NODES];       // 64 KiB
    __shared__ __align__(16) float wrow[NPB * C_NODES];     // 8 KiB: [r][j] = -w3[e(i_r,j)]

    const int t  = threadIdx.x;
    const int b0 = blockIdx.x * BT;

    // ---- stage o1t (coalesced 1KB global reads per wave-instr; swizzled LDS writes)
    {
        const int chunk = t & 63;            // 16B chunk within row
        const int c4    = chunk << 2;        // channel
        const float4 w1v = *(const float4*)&w1[c4];
        #pragma unroll
        for (int p = 0; p < 16; ++p) {
            const int row = (t >> 6) + (p << 2);          // 0..63
            const float4 xv = *(const float4*)&x[(b0 + row) * C_NODES + c4];
            float4 o;
            o.x = xv.x * w1v.x; o.y = xv.y * w1v.y;
            o.z = xv.z * w1v.z; o.w = xv.w * w1v.w;
            const int phys = chunk ^ (row & 7);
            *(float4*)&o1t[(row << 8) + (phys << 2)] = o;
        }
    }

    // ---- gather wrow[r][j] = -w3[e(i,j)]  (L2-resident scattered reads, once)
    {
        const int lane = t & 63;
        const int wv_  = t >> 6;
        #pragma unroll
        for (int rr = 0; rr < RPW; ++rr) {
            const int r = wv_ * RPW + rr;
            const int i = blockIdx.y * NPB + r;
            float4 wv;
            #pragma unroll
            for (int k = 0; k < 4; ++k) {
                const int j = lane * 4 + k;
                const int p = (i < j) ? i : j;
                const int q = (i < j) ? j : i;
                ((float*)&wv)[k] = (i == j) ? 0.f
                                 : -w3[(p * (511 - p)) / 2 + q - p - 1];
            }
            *(float4*)&wrow[(r << 8) + (lane << 2)] = wv;
        }
    }
    __syncthreads();

    const int lane    = t & 63;
    const int w       = __builtin_amdgcn_readfirstlane(t >> 6);
    const int r0      = w * RPW;
    const int i0      = blockIdx.y * NPB + r0;
    const int swz     = lane & 7;
    const int rowbase = lane << 8;

    const float c0 = w2[0], c1 = w2[1], c2 = w2[2], c3 = w2[3];

    // own-node o1 values (swizzled one-time reads)
    const float oi0 = o1t[rowbase + ((((i0 >> 2) ^ swz) << 2) | (i0 & 3))];
    const float oi1 = o1t[rowbase + (((((i0 + 1) >> 2) ^ swz) << 2) | ((i0 + 1) & 3))];

    float acc0 = 0.f, acc1 = 0.f;

    #pragma unroll 4
    for (int jc = 0; jc < 64; ++jc) {
        const float4 ov = *(const float4*)&o1t[rowbase + ((jc ^ swz) << 2)];   // 4 partners
        const float4 wa = *(const float4*)&wrow[(r0 << 8) + (jc << 2)];        // uniform
        const float4 wb = *(const float4*)&wrow[((r0 + 1) << 8) + (jc << 2)];  // uniform
        #pragma unroll
        for (int k = 0; k < 4; ++k) {
            const float oj = ((const float*)&ov)[k];
            {
                const float d   = oi0 - oj;
                const float a   = fabsf(d);
                const float t3  = __builtin_fmaf(a, __builtin_fmaf(a,
                                    __builtin_fmaf(a, c3, c2), c1), c0);
                const float t3s = fmaxf(t3, 0.01f * t3);
                acc0 = __builtin_fmaf(d * t3s, ((const float*)&wa)[k], acc0);
            }
            {
                const float d   = oi1 - oj;
                const float a   = fabsf(d);
                const float t3  = __builtin_fmaf(a, __builtin_fmaf(a,
                                    __builtin_fmaf(a, c3, c2), c1), c0);
                const float t3s = fmaxf(t3, 0.01f * t3);
                acc1 = __builtin_fmaf(d * t3s, ((const float*)&wb)[k], acc1);
            }
        }
    }

    out[(b0 + lane) * C_NODES + i0]     = acc0;
    out[(b0 + lane) * C_NODES + i0 + 1] = acc1;
}

extern "C" void kernel_launch(void* const* d_in, const int* in_sizes, int n_in,
                              void* d_out, int out_size, void* d_ws, size_t ws_size,
                              hipStream_t stream) {
    const float* x  = (const float*)d_in[0];
    const float* w1 = (const float*)d_in[1];
    const float* w2 = (const float*)d_in[2];
    const float* w3 = (const float*)d_in[3];
    float* out = (float*)d_out;

    const int B = in_sizes[0] / C_NODES;          // 1024
    dim3 grid(B / BT, C_NODES / NPB);             // 16 x 32 = 512 blocks = 2/CU
    son_kernel<<<grid, 256, 0, stream>>>(x, w1, w2, w3, out);
}

// Round 4
// 19.272 us; speedup vs baseline: 1.1730x; 1.1730x over previous
//
#include <hip/hip_runtime.h>

// Son_swapnet: out[b,i] = sum_j d*leaky01(t3)*(-w3[e(i,j)]),
//   d  = x[b,i]*w1[i] - x[b,j]*w1[j]
//   t3 = c0 + a*(c1 + a*(c2 + a*c3)), a = |d|
//   leaky01(t) = max(t, 0.01t)   [leaky factor of poly = a*t3, a>=0]
// j==i contributes exactly 0 (d==0), so the j-loop runs uniformly over all 256.

#define C_NODES 256
#define BT      64      // batches per block (one per lane)
#define NW      8       // waves per block (512 threads), 1 node per wave

__global__ __launch_bounds__(512, 4) void son_kernel(
    const float* __restrict__ x, const float* __restrict__ w1,
    const float* __restrict__ w2, const float* __restrict__ w3,
    float* __restrict__ out)
{
    // o1t: [row=batch][channel], 256 words/row, 16B-chunk XOR-swizzled by (row&7)
    __shared__ __align__(16) float o1t[BT * C_NODES];       // 64 KiB
    __shared__ __align__(16) float wrow[NW * C_NODES];      // 8 KiB: [w][j] = -w3[e(i_w,j)]

    const int t  = threadIdx.x;
    const int b0 = blockIdx.x * BT;

    // ---- stage o1t (coalesced 1KB global reads per wave-instr; swizzled LDS writes)
    {
        const int chunk = t & 63;            // 16B chunk within row
        const int c4    = chunk << 2;        // channel
        const float4 w1v = *(const float4*)&w1[c4];
        #pragma unroll
        for (int p = 0; p < 8; ++p) {
            const int row = (t >> 6) + (p << 3);          // 0..63
            const float4 xv = *(const float4*)&x[(b0 + row) * C_NODES + c4];
            float4 o;
            o.x = xv.x * w1v.x; o.y = xv.y * w1v.y;
            o.z = xv.z * w1v.z; o.w = xv.w * w1v.w;
            const int phys = chunk ^ (row & 7);
            *(float4*)&o1t[(row << 8) + (phys << 2)] = o;
        }
    }

    // ---- gather wrow[w][j] = -w3[e(i,j)]  (L2-resident scattered reads, once)
    {
        const int lane = t & 63;
        const int wv_  = t >> 6;             // wave = node slot
        const int i    = blockIdx.y * NW + wv_;
        float4 wv;
        #pragma unroll
        for (int k = 0; k < 4; ++k) {
            const int j = lane * 4 + k;
            const int p = (i < j) ? i : j;
            const int q = (i < j) ? j : i;
            ((float*)&wv)[k] = (i == j) ? 0.f
                             : -w3[(p * (511 - p)) / 2 + q - p - 1];
        }
        *(float4*)&wrow[(wv_ << 8) + (lane << 2)] = wv;
    }
    __syncthreads();

    const int lane    = t & 63;
    const int w       = __builtin_amdgcn_readfirstlane(t >> 6);
    const int i       = blockIdx.y * NW + w;
    const int swz     = lane & 7;
    const int rowbase = lane << 8;

    const float c0 = w2[0], c1 = w2[1], c2 = w2[2], c3 = w2[3];

    // own-node o1 value (swizzled one-time read)
    const float oi = o1t[rowbase + ((((i >> 2) ^ swz) << 2) | (i & 3))];

    float acc = 0.f;

    #pragma unroll 8
    for (int jc = 0; jc < 64; ++jc) {
        const float4 ov = *(const float4*)&o1t[rowbase + ((jc ^ swz) << 2)];  // 4 partners
        const float4 wa = *(const float4*)&wrow[(w << 8) + (jc << 2)];        // uniform bcast
        #pragma unroll
        for (int k = 0; k < 4; ++k) {
            const float oj  = ((const float*)&ov)[k];
            const float d   = oi - oj;
            const float a   = fabsf(d);                     // folds to abs-modifier
            const float t3  = __builtin_fmaf(a, __builtin_fmaf(a,
                                __builtin_fmaf(a, c3, c2), c1), c0);
            const float t3s = fmaxf(t3, 0.01f * t3);        // leaky on t3
            acc = __builtin_fmaf(d * t3s, ((const float*)&wa)[k], acc);
        }
    }

    out[(b0 + lane) * C_NODES + i] = acc;
}

extern "C" void kernel_launch(void* const* d_in, const int* in_sizes, int n_in,
                              void* d_out, int out_size, void* d_ws, size_t ws_size,
                              hipStream_t stream) {
    const float* x  = (const float*)d_in[0];
    const float* w1 = (const float*)d_in[1];
    const float* w2 = (const float*)d_in[2];
    const float* w3 = (const float*)d_in[3];
    float* out = (float*)d_out;

    const int B = in_sizes[0] / C_NODES;          // 1024
    dim3 grid(B / BT, C_NODES / NW);              // 16 x 32 = 512 blocks = 2/CU
    son_kernel<<<grid, 512, 0, stream>>>(x, w1, w2, w3, out);
}